// Round 4
// baseline (115.668 us; speedup 1.0000x reference)
//
#include <hip/hip_runtime.h>
#include <math.h>

#define NUM_CODE 20000
#define EMBED_D  256
#define HID      128
#define CC       64
#define NBV      3200

typedef __attribute__((ext_vector_type(8))) short bf16x8;
typedef __attribute__((ext_vector_type(4))) float f32x4;

__device__ __forceinline__ unsigned f2bf1(float f) {
    union { float f; unsigned u; } c; c.f = f;
    return (c.u + 0x7FFFu + ((c.u >> 16) & 1u)) >> 16;   // RNE
}
__device__ __forceinline__ unsigned pk2(float lo, float hi) {
    return f2bf1(lo) | (f2bf1(hi) << 16);
}
__device__ __forceinline__ float bflo(unsigned u) {
    union { unsigned u; float f; } c; c.u = u << 16; return c.f;
}
__device__ __forceinline__ float bfhi(unsigned u) {
    union { unsigned u; float f; } c; c.u = u & 0xFFFF0000u; return c.f;
}

// ---------------------------------------------------------------------------
// Kernel 0: W1 f32[128][256] -> bf16, row-major. 32 blocks x 256 thr.
// ---------------------------------------------------------------------------
__global__ __launch_bounds__(256) void w1_cvt(
    const float* __restrict__ W1, unsigned short* __restrict__ W1b)
{
    int f = blockIdx.x * 256 + threadIdx.x;
    float4 v = ((const float4*)W1)[f];
    uint2 o; o.x = pk2(v.x, v.y); o.y = pk2(v.z, v.w);
    ((uint2*)W1b)[f] = o;
}

// ---------------------------------------------------------------------------
// Kernel 1: scores via bf16 MFMA, 4-way N-split for occupancy.
// 512 threads = 8 waves = 2 M-tiles x 4 j-groups. Each wave: full K=256,
// n-tiles j = jg*2 + {0,1}. Grid 625 -> 5000 waves (4.9/SIMD).
// A frag: lane row=l&15, k=(l>>4)*8 (+s*32), f32->bf16 in-reg; jg==0 wave
// also stores the bf16 row to tbl_bf (fused table conversion).
// C layout (m89): m=(l>>4)*4+r, n=l&15.
// ---------------------------------------------------------------------------
__global__ __launch_bounds__(512) void score_mfma2(
    const float* __restrict__ table, const unsigned short* __restrict__ W1b,
    const float* __restrict__ b1, const float* __restrict__ W2,
    const float* __restrict__ b2, float* __restrict__ scores,
    unsigned short* __restrict__ tbl_bf, int write_bf)
{
    __shared__ float comb[2][3][64 * 5];   // 7680 B, pad-5: conflict-free

    const int tid  = threadIdx.x;
    const int wave = tid >> 6;
    const int t    = wave >> 2;       // M-tile 0/1
    const int jg   = wave & 3;        // n-group: j = jg*2 + jj
    const int l    = tid & 63;
    const int row  = l & 15;
    const int kg   = l >> 4;
    const int m0   = blockIdx.x * 32 + t * 16;

    const float* arow = table + (size_t)(m0 + row) * EMBED_D + kg * 8;

    f32x4 acc[2];
    acc[0] = (f32x4){0.f, 0.f, 0.f, 0.f};
    acc[1] = (f32x4){0.f, 0.f, 0.f, 0.f};

    float4 a0 = *(const float4*)(arow);
    float4 a1 = *(const float4*)(arow + 4);

#pragma unroll
    for (int s = 0; s < 8; s++) {
        float4 n0, n1;
        if (s < 7) {
            n0 = *(const float4*)(arow + (s + 1) * 32);
            n1 = *(const float4*)(arow + (s + 1) * 32 + 4);
        }
        union { uint4 u; bf16x8 v; } p;
        p.u.x = pk2(a0.x, a0.y); p.u.y = pk2(a0.z, a0.w);
        p.u.z = pk2(a1.x, a1.y); p.u.w = pk2(a1.z, a1.w);
        if (write_bf && jg == 0)
            *(uint4*)(tbl_bf + (size_t)(m0 + row) * EMBED_D + s * 32 + kg * 8) = p.u;
#pragma unroll
        for (int jj = 0; jj < 2; jj++) {
            int j = jg * 2 + jj;
            bf16x8 bf = *(const bf16x8*)(W1b + (size_t)(j * 16 + row) * EMBED_D + s * 32 + kg * 8);
            acc[jj] = __builtin_amdgcn_mfma_f32_16x16x32_bf16(p.v, bf, acc[jj], 0, 0, 0);
        }
        a0 = n0; a1 = n1;
    }

    // partial epilogue over this wave's 2 n-tiles
    float part[4];
#pragma unroll
    for (int r = 0; r < 4; r++) part[r] = 0.f;
#pragma unroll
    for (int jj = 0; jj < 2; jj++) {
        int j = jg * 2 + jj;
        float w2 = W2[j * 16 + row];
        float bb = b1[j * 16 + row];
#pragma unroll
        for (int r = 0; r < 4; r++)
            part[r] += w2 * tanhf(acc[jj][r] + bb);
    }

    if (jg != 0) {
#pragma unroll
        for (int r = 0; r < 4; r++)
            comb[t][jg - 1][l * 5 + r] = part[r];
    }
    __syncthreads();
    if (jg == 0) {
#pragma unroll
        for (int g2 = 0; g2 < 3; g2++)
#pragma unroll
            for (int r = 0; r < 4; r++)
                part[r] += comb[t][g2][l * 5 + r];
        // reduce over the 16 'row' lanes (preserves kg)
#pragma unroll
        for (int r = 0; r < 4; r++) {
#pragma unroll
            for (int o = 1; o < 16; o <<= 1)
                part[r] += __shfl_xor(part[r], o, 16);
        }
        if (row == 0) {
            float b2v = b2[0];
            float4 o4 = make_float4(part[0] + b2v, part[1] + b2v,
                                    part[2] + b2v, part[3] + b2v);
            *(float4*)&scores[m0 + kg * 4] = o4;
        }
    }
}

// ---------------------------------------------------------------------------
// Kernel 2: per (b,v) row — masked softmax over 64 scores, weighted sum of
// bf16 embeddings. 8 groups x 32 lanes, dwordx4 coalesced row reads,
// gathers issued before softmax. float4 LDS reduce writes.
// ---------------------------------------------------------------------------
__global__ __launch_bounds__(256) void attn_v4(
    const int* __restrict__ codes, const int* __restrict__ lens,
    const uint4* __restrict__ t16, const float* __restrict__ scores,
    float* __restrict__ out)
{
    __shared__ float attn_s[CC];
    __shared__ int   code_s[CC];
    __shared__ float red[8][256];

    const int bv  = blockIdx.x;
    const int tid = threadIdx.x;
    const int g   = tid >> 5;
    const int l   = tid & 31;

    int c_reg = 0;
    if (tid < CC) {
        c_reg = codes[(size_t)bv * CC + tid];
        code_s[tid] = c_reg;
    }
    __syncthreads();

    uint4 v[8];
#pragma unroll
    for (int cc = 0; cc < 8; cc++)
        v[cc] = t16[(size_t)code_s[cc * 8 + g] * 32 + l];

    if (tid < CC) {
        float sc  = scores[c_reg];
        int   len = lens[bv];
        float val = (tid < len) ? sc : -1e9f;
        float m = val;
#pragma unroll
        for (int o = 32; o >= 1; o >>= 1)
            m = fmaxf(m, __shfl_xor(m, o, 64));
        float e = expf(val - m);
        float sum = e;
#pragma unroll
        for (int o = 32; o >= 1; o >>= 1)
            sum += __shfl_xor(sum, o, 64);
        attn_s[tid] = e / sum;
    }
    __syncthreads();

    float acc[8] = {0.f, 0.f, 0.f, 0.f, 0.f, 0.f, 0.f, 0.f};
#pragma unroll
    for (int cc = 0; cc < 8; cc++) {
        float a = attn_s[cc * 8 + g];
        unsigned u;
        u = v[cc].x; acc[0] += a * bflo(u); acc[1] += a * bfhi(u);
        u = v[cc].y; acc[2] += a * bflo(u); acc[3] += a * bfhi(u);
        u = v[cc].z; acc[4] += a * bflo(u); acc[5] += a * bfhi(u);
        u = v[cc].w; acc[6] += a * bflo(u); acc[7] += a * bfhi(u);
    }
    *(float4*)&red[g][l * 8]     = make_float4(acc[0], acc[1], acc[2], acc[3]);
    *(float4*)&red[g][l * 8 + 4] = make_float4(acc[4], acc[5], acc[6], acc[7]);
    __syncthreads();

    if (tid < 64) {
        float4 o = make_float4(0.f, 0.f, 0.f, 0.f);
#pragma unroll
        for (int g2 = 0; g2 < 8; g2++) {
            float4 r = *(const float4*)&red[g2][tid * 4];
            o.x += r.x; o.y += r.y; o.z += r.z; o.w += r.w;
        }
        ((float4*)out)[(size_t)bv * 64 + tid] = o;
    }
}

// f32 fallback attn (only if d_ws can't hold the bf16 table)
__global__ __launch_bounds__(256) void attn_f32(
    const int* __restrict__ codes, const int* __restrict__ lens,
    const float* __restrict__ table, const float* __restrict__ scores,
    float* __restrict__ out)
{
    __shared__ float attn_s[CC];
    __shared__ int   code_s[CC];
    __shared__ float4 red4[3][64];

    const int bv  = blockIdx.x;
    const int tid = threadIdx.x;

    if (tid < CC) {
        int c = codes[(size_t)bv * CC + tid];
        code_s[tid] = c;
        float sc  = scores[c];
        int   len = lens[bv];
        float val = (tid < len) ? sc : -1e9f;
        float m = val;
#pragma unroll
        for (int o = 32; o >= 1; o >>= 1)
            m = fmaxf(m, __shfl_xor(m, o, 64));
        float e = expf(val - m);
        float sum = e;
#pragma unroll
        for (int o = 32; o >= 1; o >>= 1)
            sum += __shfl_xor(sum, o, 64);
        attn_s[tid] = e / sum;
    }
    __syncthreads();

    const int g = tid >> 6;
    const int l = tid & 63;
    const float4* t4 = (const float4*)table;
    float4 acc = make_float4(0.f, 0.f, 0.f, 0.f);
#pragma unroll
    for (int cc = 0; cc < 16; cc++) {
        int c   = cc * 4 + g;
        float a = attn_s[c];
        float4 vv = t4[(size_t)code_s[c] * 64 + l];
        acc.x += a * vv.x; acc.y += a * vv.y; acc.z += a * vv.z; acc.w += a * vv.w;
    }
    if (g > 0) red4[g - 1][l] = acc;
    __syncthreads();
    if (g == 0) {
#pragma unroll
        for (int r = 0; r < 3; r++) {
            float4 vv = red4[r][l];
            acc.x += vv.x; acc.y += vv.y; acc.z += vv.z; acc.w += vv.w;
        }
        ((float4*)out)[(size_t)bv * 64 + l] = acc;
    }
}

extern "C" void kernel_launch(void* const* d_in, const int* in_sizes, int n_in,
                              void* d_out, int out_size, void* d_ws, size_t ws_size,
                              hipStream_t stream) {
    const int*   input_code  = (const int*)d_in[0];   // [64,50,64]
    const int*   length_code = (const int*)d_in[1];   // [64,50]
    const float* embed_table = (const float*)d_in[2]; // [20000,256]
    const float* W1 = (const float*)d_in[3];          // [128,256]
    const float* b1 = (const float*)d_in[4];          // [128]
    const float* W2 = (const float*)d_in[5];          // [1,128]
    const float* b2 = (const float*)d_in[6];          // [1]
    float* out = (float*)d_out;                       // [64,50,256]

    // ws layout: scores (80 KB) | W1b (64 KB) | tbl_bf (10.24 MB)
    float*          scores = (float*)d_ws;
    unsigned short* W1b    = (unsigned short*)((char*)d_ws + 81920);
    unsigned short* tbl_bf = (unsigned short*)((char*)d_ws + 81920 + 65536);
    const size_t need_full = 81920 + 65536 + (size_t)NUM_CODE * EMBED_D * 2;
    const int use_bf = (ws_size >= need_full) ? 1 : 0;

    w1_cvt<<<32, 256, 0, stream>>>(W1, W1b);
    score_mfma2<<<NUM_CODE / 32, 512, 0, stream>>>(
        embed_table, W1b, b1, W2, b2, scores, tbl_bf, use_bf);
    if (use_bf)
        attn_v4<<<NBV, 256, 0, stream>>>(input_code, length_code,
                                         (const uint4*)tbl_bf, scores, out);
    else
        attn_f32<<<NBV, 256, 0, stream>>>(input_code, length_code,
                                          embed_table, scores, out);
}